// Round 19
// baseline (190.238 us; speedup 1.0000x reference)
//
#include <hip/hip_runtime.h>
#include <hip/hip_bf16.h>

// ---------------------------------------------------------------------------
// AttentionHead B=4,S=2048,D=1024 — round 19.
// NEW gemmF<AF32,BF32>: gemmO skeleton (256x128, BK=32, 3-deep, counted
// vmcnt) staging the f32 operand DIRECTLY from d_in (f32 row = 128B = 8
// chunks, gemm8p's proven swizzle geometry) and converting fragments
// f32->f16 at LDS-read time. Eliminates the X-convert pass entirely
// (prep becomes W-only): saves ~27us prep + 96MB traffic.
// KQ-proj = gemmF<A=f32 X, B=f16 WT>; VT-proj = gemmF<A=f16 WT_V, B=f32 Xv>.
// scores (gemm8p), softmax, PV (gemmO) unchanged from r18.
// ws (MiB): WT@0(6) PROJ@6(32: K,Q) VTf@38(16) SC@54(32,f16) P@70(32,f16).
// high-water 102 MiB.
// ---------------------------------------------------------------------------

typedef __attribute__((ext_vector_type(4))) float    f32x4;
typedef __attribute__((ext_vector_type(8))) _Float16 f16x8;
typedef __attribute__((ext_vector_type(4))) _Float16 f16x4;

constexpr size_t MiB = 1u << 20;
constexpr size_t MK  = (size_t)8192 * 1024;
constexpr size_t WSZ = (size_t)1024 * 1024;

__device__ __forceinline__ void gload_lds16(const void* g, void* l) {
  __builtin_amdgcn_global_load_lds(
      (const __attribute__((address_space(1))) unsigned int*)g,
      (__attribute__((address_space(3))) unsigned int*)l, 16, 0, 0);
}

#define MFMA16(a, b, c) __builtin_amdgcn_mfma_f32_16x16x32_f16(a, b, c, 0, 0, 0)

// XCD-chunked bijective block swizzle (requires total blocks % 8 == 0).
__device__ __forceinline__ void swz_block(int& bx, int& by, int& bz) {
  unsigned gx = gridDim.x, gy = gridDim.y;
  unsigned flat = blockIdx.x + gx * (blockIdx.y + gy * blockIdx.z);
  unsigned total = gx * gy * gridDim.z;
  unsigned cpx = total >> 3;
  unsigned s = (flat & 7) * cpx + (flat >> 3);
  bx = s % gx; s /= gx; by = s % gy; bz = s / gy;
}

// ---------------------------------------------------------------------------
// prepW: W -> W^T f16 only (64x64 tiles; r18-verified). 768 blocks.
__global__ __launch_bounds__(256) void prepW(
    const float* __restrict__ w0, const float* __restrict__ w1,
    const float* __restrict__ w2, _Float16* __restrict__ WT)
{
  const unsigned id = blockIdx.x;
  const int tid = threadIdx.x;
  const int z = id >> 8;
  const unsigned blk = id & 255;
  const float* W = z == 0 ? w0 : (z == 1 ? w1 : w2);
  _Float16* o = WT + (size_t)z * WSZ;
  __shared__ float tile[64][65];
  const int bx = (blk & 15) * 64;      // n
  const int by = (blk >> 4) * 64;      // k
  const int tx = tid & 15, ty = tid >> 4;
  #pragma unroll
  for (int p = 0; p < 4; ++p) {
    f32x4 v = *(const f32x4*)(&W[(size_t)(by + ty + 16 * p) * 1024 + bx + 4 * tx]);
    tile[ty + 16 * p][4 * tx + 0] = v.x;
    tile[ty + 16 * p][4 * tx + 1] = v.y;
    tile[ty + 16 * p][4 * tx + 2] = v.z;
    tile[ty + 16 * p][4 * tx + 3] = v.w;
  }
  __syncthreads();
  const int rr = tid >> 3, cc = tid & 7;
  #pragma unroll
  for (int q = 0; q < 2; ++q) {
    const int nl = rr + 32 * q;
    f16x8 h;
    #pragma unroll
    for (int j = 0; j < 8; ++j) h[j] = (_Float16)tile[8 * cc + j][nl];
    *(f16x8*)(&o[(size_t)(bx + nl) * 1024 + by + 8 * cc]) = h;
  }
}

// ---------------------------------------------------------------------------
// gemmF: C[m][n](f16) = sum_k A[m][k]*B[n][k]; A/B independently f32 or f16.
// 256(M)x128(N), BK=32, 512 thr = 8 waves (4M x 2N), 3-deep pipeline.
// f32 rows = 128B = 8 chunks: staging clog=(t&7)^((t>>3)&7) (gemm8p-proven),
// fragment phys chunk (2fq+j)^(fr&7); f16 sides identical to gemmO.
// A/B base selected by bz (A0/A1, B0/B1); C += bz*sCz.
template <bool AF32, bool BF32>
__global__ __launch_bounds__(512, 2) void gemmF(
    const void* __restrict__ A0v, const void* __restrict__ A1v, int lda,
    const void* __restrict__ B0v, const void* __restrict__ B1v, int ldb,
    _Float16* __restrict__ Cp, size_t sCz, int ldc, int K)
{
  extern __shared__ char lds[];
  constexpr int PA  = 256 * (AF32 ? 128 : 64);   // A panel bytes
  constexpr int PB  = 128 * (BF32 ? 128 : 64);   // B panel bytes
  constexpr int BUF = PA + PB;
  constexpr int LPT = (AF32 ? 4 : 2) + (BF32 ? 2 : 1);

  int bx, by, bz;
  swz_block(bx, by, bz);
  const void* Av = bz == 0 ? A0v : A1v;
  const void* Bv = bz == 0 ? B0v : B1v;
  _Float16* C = Cp + (size_t)bz * sCz;

  const int gm0 = by * 256, gn0 = bx * 128;
  const int tid = threadIdx.x;
  const int lane = tid & 63, wave = tid >> 6;
  const int wm = (wave >> 1) * 64;
  const int wn = (wave & 1) * 64;
  const int fr = lane & 15, fq = lane >> 4;
  const int nkt = K >> 5;

  // staging source pointers
  const float*    sA32 = AF32 ? (const float*)Av + (size_t)(gm0 + (tid >> 3)) * lda
                                 + (((tid & 7) ^ ((tid >> 3) & 7)) * 4) : nullptr;
  const _Float16* sA16 = AF32 ? nullptr : (const _Float16*)Av + (size_t)(gm0 + (tid >> 2)) * lda
                                 + (((tid & 3) ^ ((tid >> 3) & 3)) * 8);
  const float*    sB32 = BF32 ? (const float*)Bv + (size_t)(gn0 + (tid >> 3)) * ldb
                                 + (((tid & 7) ^ ((tid >> 3) & 7)) * 4) : nullptr;
  const _Float16* sB16 = BF32 ? nullptr : (const _Float16*)Bv + (size_t)(gn0 + (tid >> 2)) * ldb
                                 + (((tid & 3) ^ ((tid >> 3) & 3)) * 8);
  char* const dst0 = lds + tid * 16;

  auto STG = [&](int tile) {
    char* base = dst0 + (tile % 3) * BUF;
    const int ko = tile * 32;
    if constexpr (AF32) {
      #pragma unroll
      for (int g = 0; g < 4; ++g)
        gload_lds16(sA32 + (size_t)g * 64 * lda + ko, base + g * 8192);
    } else {
      gload_lds16(sA16 + ko,                        base);
      gload_lds16(sA16 + (size_t)128 * lda + ko,    base + 8192);
    }
    if constexpr (BF32) {
      #pragma unroll
      for (int g = 0; g < 2; ++g)
        gload_lds16(sB32 + (size_t)g * 64 * ldb + ko, base + PA + g * 8192);
    } else {
      gload_lds16(sB16 + ko, base + PA);
    }
  };

#define WAIT_LPT                                                      \
  if constexpr (LPT == 5) asm volatile("s_waitcnt vmcnt(5)" ::: "memory"); \
  else if constexpr (LPT == 4) asm volatile("s_waitcnt vmcnt(4)" ::: "memory"); \
  else asm volatile("s_waitcnt vmcnt(3)" ::: "memory");

  // fragment read offsets
  const int ax = fr & 7;
  const int aLo = ((2 * fq) ^ ax) * 16, aHi = ((2 * fq + 1) ^ ax) * 16;   // f32
  const int p16 = (fq ^ ((fr >> 1) & 3)) * 16;                            // f16
  const int arb = AF32 ? (wm + fr) * 128 : (wm + fr) * 64 + p16;
  const int brb = BF32 ? PA + (wn + fr) * 128 : PA + (wn + fr) * 64 + p16;

  f32x4 acc[4][4] = {};
  f16x8 af[4], bfr[4];

  STG(0);
  if (nkt > 1) {
    STG(1);
    WAIT_LPT
  } else {
    asm volatile("s_waitcnt vmcnt(0)" ::: "memory");
  }
  __builtin_amdgcn_s_barrier();
  __builtin_amdgcn_sched_barrier(0);

  for (int t = 0; t < nkt; ++t) {
    const char* buf = lds + (t % 3) * BUF;
    const bool st2 = (t + 2) < nkt;

    if (st2) STG(t + 2);

    #pragma unroll
    for (int mi = 0; mi < 4; ++mi) {
      if constexpr (AF32) {
        f32x4 lo = *(const f32x4*)(buf + arb + mi * 2048 + aLo);
        f32x4 hi = *(const f32x4*)(buf + arb + mi * 2048 + aHi);
        af[mi] = {(_Float16)lo.x, (_Float16)lo.y, (_Float16)lo.z, (_Float16)lo.w,
                  (_Float16)hi.x, (_Float16)hi.y, (_Float16)hi.z, (_Float16)hi.w};
      } else {
        af[mi] = *(const f16x8*)(buf + arb + mi * 1024);
      }
    }
    #pragma unroll
    for (int ni = 0; ni < 4; ++ni) {
      if constexpr (BF32) {
        f32x4 lo = *(const f32x4*)(buf + brb + ni * 2048 + aLo);
        f32x4 hi = *(const f32x4*)(buf + brb + ni * 2048 + aHi);
        bfr[ni] = {(_Float16)lo.x, (_Float16)lo.y, (_Float16)lo.z, (_Float16)lo.w,
                   (_Float16)hi.x, (_Float16)hi.y, (_Float16)hi.z, (_Float16)hi.w};
      } else {
        bfr[ni] = *(const f16x8*)(buf + brb + ni * 1024);
      }
    }

    __builtin_amdgcn_s_setprio(1);
    #pragma unroll
    for (int mi = 0; mi < 4; ++mi)
      #pragma unroll
      for (int ni = 0; ni < 4; ++ni)
        acc[mi][ni] = MFMA16(af[mi], bfr[ni], acc[mi][ni]);
    __builtin_amdgcn_s_setprio(0);

    if (st2) { WAIT_LPT }
    else if (t + 1 < nkt) asm volatile("s_waitcnt vmcnt(0)" ::: "memory");
    __builtin_amdgcn_s_barrier();
    __builtin_amdgcn_sched_barrier(0);
  }
#undef WAIT_LPT

  const int erow = gm0 + wm + fq * 4;
  const int ecol = gn0 + wn + fr;
  #pragma unroll
  for (int m = 0; m < 4; ++m)
    #pragma unroll
    for (int n = 0; n < 4; ++n) {
      size_t base = (size_t)(erow + m * 16) * ldc + (ecol + n * 16);
      #pragma unroll
      for (int r = 0; r < 4; ++r)
        C[base + (size_t)r * ldc] = (_Float16)acc[m][n][r];
    }
}

// ---------------------------------------------------------------------------
// gemm8p (r7 verbatim): 256x256 BK=64, 4 phases/K-tile. For scores.
// MODE 2: f16*scale.
template <int MODE>
__global__ __launch_bounds__(512, 2) void gemm8p(
    const _Float16* __restrict__ At, size_t sA,
    const _Float16* __restrict__ Bt, size_t sB,
    void* __restrict__ Cv, size_t sCz,
    int N, int K, float scale)
{
  extern __shared__ char lds[];
  int bx, by, bz;
  swz_block(bx, by, bz);
  const _Float16* A = At + (size_t)bz * sA;
  const _Float16* B = Bt + (size_t)bz * sB;

  const int gm0 = by * 256, gn0 = bx * 256;
  const int tid = threadIdx.x;
  const int lane = tid & 63, wave = tid >> 6;
  const int wm = (wave >> 2) * 128;
  const int wn = (wave & 3) * 64;
  const int fr = lane & 15, fq = lane >> 4;
  const int nkt = K >> 6;

  const int clog = ((tid & 7) ^ ((tid >> 3) & 7)) * 8;
  const _Float16* srcA = A + (size_t)(gm0 + (tid >> 3)) * K + clog;
  const _Float16* srcB = B + (size_t)(gn0 + (tid >> 3)) * K + clog;
  char* const dst0 = lds + tid * 16;

  auto SH = [&](int tile, int h) {
    const _Float16* s = (h < 2 ? srcA : srcB) + (size_t)((h & 1) * 128) * K
                        + tile * 64;
    char* d = dst0 + (tile & 1) * 65536 + h * 16384;
    gload_lds16(s, d);
    gload_lds16(s + (size_t)64 * K, d + 8192);
  };

  const int axor = fr & 7;
  const int pc0 = (fq ^ axor) * 16;
  const int pc1 = ((4 + fq) ^ axor) * 16;
  const int arb = (wm + fr) * 128;
  const int brb = 32768 + (wn + fr) * 128;

  f32x4 acc[8][4] = {};
  f16x8 af[4][2], b0[2][2], b1[2][2];

  SH(0, 0); SH(0, 1); SH(0, 2); SH(0, 3);
  if (nkt > 1) {
    SH(1, 0);
    asm volatile("s_waitcnt vmcnt(2)" ::: "memory");
  } else {
    asm volatile("s_waitcnt vmcnt(0)" ::: "memory");
  }
  __builtin_amdgcn_s_barrier();
  __builtin_amdgcn_sched_barrier(0);

#define PHASE_MID                                          \
  __builtin_amdgcn_s_barrier();                            \
  asm volatile("s_waitcnt lgkmcnt(0)" ::: "memory");       \
  __builtin_amdgcn_sched_barrier(0);                       \
  __builtin_amdgcn_s_setprio(1);
#define PHASE_END                                          \
  __builtin_amdgcn_s_setprio(0);                           \
  __builtin_amdgcn_sched_barrier(0);                       \
  __builtin_amdgcn_s_barrier();

  for (int t = 0; t < nkt; ++t) {
    const char* buf = lds + (t & 1) * 65536;
    const bool st1 = (t + 1) < nkt;

    #pragma unroll
    for (int mi = 0; mi < 4; ++mi) {
      af[mi][0] = *(const f16x8*)(buf + arb + mi * 2048 + pc0);
      af[mi][1] = *(const f16x8*)(buf + arb + mi * 2048 + pc1);
    }
    #pragma unroll
    for (int ni = 0; ni < 2; ++ni) {
      b0[ni][0] = *(const f16x8*)(buf + brb + ni * 2048 + pc0);
      b0[ni][1] = *(const f16x8*)(buf + brb + ni * 2048 + pc1);
    }
    if (st1) SH(t + 1, 1);
    PHASE_MID
    #pragma unroll
    for (int mi = 0; mi < 4; ++mi)
      #pragma unroll
      for (int ni = 0; ni < 2; ++ni)
        #pragma unroll
        for (int kk = 0; kk < 2; ++kk)
          acc[mi][ni] = MFMA16(af[mi][kk], b0[ni][kk], acc[mi][ni]);
    PHASE_END

    #pragma unroll
    for (int ni = 0; ni < 2; ++ni) {
      b1[ni][0] = *(const f16x8*)(buf + brb + (ni + 2) * 2048 + pc0);
      b1[ni][1] = *(const f16x8*)(buf + brb + (ni + 2) * 2048 + pc1);
    }
    if (st1) SH(t + 1, 2);
    PHASE_MID
    #pragma unroll
    for (int mi = 0; mi < 4; ++mi)
      #pragma unroll
      for (int ni = 0; ni < 2; ++ni)
        #pragma unroll
        for (int kk = 0; kk < 2; ++kk)
          acc[mi][ni + 2] = MFMA16(af[mi][kk], b1[ni][kk], acc[mi][ni + 2]);
    PHASE_END

    #pragma unroll
    for (int mi = 0; mi < 4; ++mi) {
      af[mi][0] = *(const f16x8*)(buf + arb + (mi + 4) * 2048 + pc0);
      af[mi][1] = *(const f16x8*)(buf + arb + (mi + 4) * 2048 + pc1);
    }
    if (st1) SH(t + 1, 3);
    PHASE_MID
    #pragma unroll
    for (int mi = 0; mi < 4; ++mi)
      #pragma unroll
      for (int ni = 0; ni < 2; ++ni)
        #pragma unroll
        for (int kk = 0; kk < 2; ++kk)
          acc[mi + 4][ni] = MFMA16(af[mi][kk], b0[ni][kk], acc[mi + 4][ni]);
    PHASE_END

    const bool st2 = (t + 2) < nkt;
    if (st2) SH(t + 2, 0);
    __builtin_amdgcn_s_barrier();
    __builtin_amdgcn_s_setprio(1);
    #pragma unroll
    for (int mi = 0; mi < 4; ++mi)
      #pragma unroll
      for (int ni = 0; ni < 2; ++ni)
        #pragma unroll
        for (int kk = 0; kk < 2; ++kk)
          acc[mi + 4][ni + 2] = MFMA16(af[mi][kk], b1[ni][kk], acc[mi + 4][ni + 2]);
    __builtin_amdgcn_s_setprio(0);
    __builtin_amdgcn_sched_barrier(0);
    if (st2) asm volatile("s_waitcnt vmcnt(2)" ::: "memory");
    else     asm volatile("s_waitcnt vmcnt(0)" ::: "memory");
    __builtin_amdgcn_s_barrier();
  }
#undef PHASE_MID
#undef PHASE_END

  const int erow = gm0 + wm + fq * 4;
  const int ecol = gn0 + wn + fr;
  #pragma unroll
  for (int m = 0; m < 8; ++m)
    #pragma unroll
    for (int n = 0; n < 4; ++n) {
      size_t base = (size_t)(erow + m * 16) * N + (ecol + n * 16);
      #pragma unroll
      for (int r = 0; r < 4; ++r) {
        float v = acc[m][n][r];
        if constexpr (MODE == 0)
          ((float*)Cv + (size_t)bz * sCz)[base + (size_t)r * N] = v * scale;
        else if constexpr (MODE == 1)
          ((_Float16*)Cv + (size_t)bz * sCz)[base + (size_t)r * N] = (_Float16)v;
        else
          ((_Float16*)Cv + (size_t)bz * sCz)[base + (size_t)r * N] =
              (_Float16)(v * scale);
      }
    }
}

// ---------------------------------------------------------------------------
// gemmO (r14 verbatim): 256x128, BK=32, 3-deep, 72KiB, lda/ldb/ldc. For PV.
template <int MODE>
__global__ __launch_bounds__(512, 4) void gemmO(
    const _Float16* __restrict__ At, size_t sAz, int lda,
    const _Float16* __restrict__ Bt, size_t sBz, int ldb,
    void* __restrict__ Cv, size_t sCz, int ldc,
    int K, float scale)
{
  extern __shared__ char lds[];
  int bx, by, bz;
  swz_block(bx, by, bz);
  const _Float16* A = At + (size_t)bz * sAz;
  const _Float16* B = Bt + (size_t)bz * sBz;

  const int gm0 = by * 256, gn0 = bx * 128;
  const int tid = threadIdx.x;
  const int lane = tid & 63, wave = tid >> 6;
  const int wm = (wave >> 1) * 64;
  const int wn = (wave & 1) * 64;
  const int fr = lane & 15, fq = lane >> 4;
  const int nkt = K >> 5;

  const int clog = ((tid & 3) ^ ((tid >> 3) & 3)) * 8;
  const _Float16* srcA = A + (size_t)(gm0 + (tid >> 2)) * lda + clog;
  const _Float16* srcB = B + (size_t)(gn0 + (tid >> 2)) * ldb + clog;
  char* const dst0 = lds + tid * 16;

  auto STG = [&](int tile) {
    const int off = tile * 32;
    char* d = dst0 + (tile % 3) * 24576;
    gload_lds16(srcA + off,                     d);
    gload_lds16(srcA + off + (size_t)128 * lda, d + 8192);
    gload_lds16(srcB + off,                     d + 16384);
  };

  const int pc  = (fq ^ ((fr >> 1) & 3)) * 16;
  const int arb = (wm + fr) * 64 + pc;
  const int brb = 16384 + (wn + fr) * 64 + pc;

  f32x4 acc[4][4] = {};
  f16x8 af[4], bfr[4];

  STG(0);
  if (nkt > 1) {
    STG(1);
    asm volatile("s_waitcnt vmcnt(3)" ::: "memory");
  } else {
    asm volatile("s_waitcnt vmcnt(0)" ::: "memory");
  }
  __builtin_amdgcn_s_barrier();
  __builtin_amdgcn_sched_barrier(0);

  for (int t = 0; t < nkt; ++t) {
    const char* buf = lds + (t % 3) * 24576;
    const bool st2 = (t + 2) < nkt;

    if (st2) STG(t + 2);

    #pragma unroll
    for (int mi = 0; mi < 4; ++mi)
      af[mi] = *(const f16x8*)(buf + arb + mi * 1024);
    #pragma unroll
    for (int ni = 0; ni < 4; ++ni)
      bfr[ni] = *(const f16x8*)(buf + brb + ni * 1024);

    __builtin_amdgcn_s_setprio(1);
    #pragma unroll
    for (int mi = 0; mi < 4; ++mi)
      #pragma unroll
      for (int ni = 0; ni < 4; ++ni)
        acc[mi][ni] = MFMA16(af[mi], bfr[ni], acc[mi][ni]);
    __builtin_amdgcn_s_setprio(0);

    if (st2)               asm volatile("s_waitcnt vmcnt(3)" ::: "memory");
    else if (t + 1 < nkt)  asm volatile("s_waitcnt vmcnt(0)" ::: "memory");
    __builtin_amdgcn_s_barrier();
    __builtin_amdgcn_sched_barrier(0);
  }

  const int erow = gm0 + wm + fq * 4;
  const int ecol = gn0 + wn + fr;
  #pragma unroll
  for (int m = 0; m < 4; ++m)
    #pragma unroll
    for (int n = 0; n < 4; ++n) {
      size_t base = (size_t)(erow + m * 16) * ldc + (ecol + n * 16);
      #pragma unroll
      for (int r = 0; r < 4; ++r) {
        float v = acc[m][n][r];
        size_t idx = base + (size_t)r * ldc;
        if constexpr (MODE == 0)
          ((float*)Cv + (size_t)bz * sCz)[idx] = v * scale;
        else
          ((_Float16*)Cv + (size_t)bz * sCz)[idx] = (_Float16)(v * scale);
      }
    }
}

// ---------------------------------------------------------------------------
// Wave-per-row softmax: scores [8192 rows][2048] f16 -> P f16. 8 rows/block.
__global__ __launch_bounds__(512) void softmax_rows(
    const _Float16* __restrict__ S, _Float16* __restrict__ P)
{
  const int w = threadIdx.x >> 6, lane = threadIdx.x & 63;
  const size_t row = (size_t)blockIdx.x * 8 + w;
  const _Float16* sr = S + row * 2048;

  f16x8 v[4];
  #pragma unroll
  for (int c = 0; c < 4; ++c)
    v[c] = *(const f16x8*)(sr + c * 512 + lane * 8);

  float m = -1e30f;
  #pragma unroll
  for (int c = 0; c < 4; ++c)
    #pragma unroll
    for (int j = 0; j < 8; ++j) m = fmaxf(m, (float)v[c][j]);
  #pragma unroll
  for (int o = 32; o >= 1; o >>= 1) m = fmaxf(m, __shfl_xor(m, o));

  float e[4][8];
  float s = 0.f;
  #pragma unroll
  for (int c = 0; c < 4; ++c)
    #pragma unroll
    for (int j = 0; j < 8; ++j) {
      e[c][j] = __expf((float)v[c][j] - m);
      s += e[c][j];
    }
  #pragma unroll
  for (int o = 32; o >= 1; o >>= 1) s += __shfl_xor(s, o);

  const float inv = 1.0f / s;
  _Float16* pr = P + row * 2048;
  #pragma unroll
  for (int c = 0; c < 4; ++c) {
    f16x8 p;
    #pragma unroll
    for (int j = 0; j < 8; ++j) p[j] = (_Float16)(e[c][j] * inv);
    *(f16x8*)(pr + c * 512 + lane * 8) = p;
  }
}

// ---------------------------------------------------------------------------
extern "C" void kernel_launch(void* const* d_in, const int* in_sizes, int n_in,
                              void* d_out, int out_size, void* d_ws, size_t ws_size,
                              hipStream_t stream)
{
  const float* Xk = (const float*)d_in[0];
  const float* Xv = (const float*)d_in[1];
  const float* Xq = (const float*)d_in[2];
  const float* WK = (const float*)d_in[3];
  const float* WV = (const float*)d_in[4];
  const float* WQ = (const float*)d_in[5];
  float* out = (float*)d_out;
  char* ws = (char*)d_ws;

  _Float16* WT   = (_Float16*)(ws);               // 0..6 MiB (K,V,Q)
  _Float16* PROJ = (_Float16*)(ws + 6 * MiB);     // 6..38 (K,Q)
  _Float16* VTf  = (_Float16*)(ws + 38 * MiB);    // 38..54 [1024][8192]
  _Float16* SC   = (_Float16*)(ws + 54 * MiB);    // 54..86 (f16 scores)
  _Float16* P    = (_Float16*)(ws + 70 * MiB + 16 * MiB);  // 86..118

  _Float16* Kp = PROJ;            // [8192][1024]
  _Float16* Qp = PROJ + MK;       // [8192][1024]

  auto* fKQ = gemmF<true, false>;
  auto* fVT = gemmF<false, true>;
  auto* gSC = gemm8p<2>;
  auto* fPV = gemmO<0>;
  (void)hipFuncSetAttribute((const void*)fKQ, hipFuncAttributeMaxDynamicSharedMemorySize, 122880);
  (void)hipFuncSetAttribute((const void*)fVT, hipFuncAttributeMaxDynamicSharedMemorySize, 98304);
  (void)hipFuncSetAttribute((const void*)gSC, hipFuncAttributeMaxDynamicSharedMemorySize, 131072);
  (void)hipFuncSetAttribute((const void*)fPV, hipFuncAttributeMaxDynamicSharedMemorySize, 73728);

  // 1) W -> W^T f16 only
  prepW<<<dim3(768), 256, 0, stream>>>(WK, WV, WQ, WT);
  // 2) K,Q projections directly from f32 X: z=0 -> Kp (Xk,WT_K), z=1 -> Qp
  //    (Xq,WT_Q). grid (8,32,2) = 512 blocks.
  gemmF<true, false><<<dim3(8, 32, 2), 512, 122880, stream>>>(
      Xk, Xq, 1024, WT, WT + 2 * WSZ, 1024,
      PROJ, MK, 1024, 1024);
  // 3) V^T projection directly from f32 Xv: VTf[e][s] = sum_k WT_V[e][k]*Xv[s][k]
  gemmF<false, true><<<dim3(64, 4, 1), 512, 98304, stream>>>(
      WT + WSZ, WT + WSZ, 1024, Xv, Xv, 1024,
      VTf, 0, 8192, 1024);
  // 4) scores[b] = Q[b]@K[b]^T / sqrt(2048) -> f16  (256 blocks)
  gemm8p<2><<<dim3(8, 8, 4), 512, 131072, stream>>>(
      Qp, (size_t)2048 * 1024, Kp, (size_t)2048 * 1024,
      SC, (size_t)2048 * 2048, 2048, 1024, 0.022097086912079608f);
  // 5) softmax (wave-per-row, 8 rows/block) -> P f16
  softmax_rows<<<dim3(1024), 512, 0, stream>>>(SC, P);
  // 6) out[b] = P[b] @ V[b]: C[m][e] = sum_k P[m][k] * VTf[e][b*2048+k]
  gemmO<0><<<dim3(8, 8, 4), 512, 73728, stream>>>(
      P, (size_t)2048 * 2048, 2048, VTf, 2048, 8192,
      out, (size_t)2048 * 1024, 1024, 2048, 1.0f);
}

// Round 20
// 186.122 us; speedup vs baseline: 1.0221x; 1.0221x over previous
//
#include <hip/hip_runtime.h>
#include <hip/hip_bf16.h>

// ---------------------------------------------------------------------------
// AttentionHead B=4,S=2048,D=1024 — round 20. REVERT to best-measured parts:
// prep (r18: W-first 64x64 + NT X-convert), KQ+scores on gemm8p (r7),
// VT-proj + PV on gemmO (r14). ONE change: VT-proj writes per-batch
// contiguous VTb[4][1024][2048] (grid (16,4,4)) so PV's B is ldb=2048
// contiguous — fixes PV's 394-TF L2-thrash (B rows were 16KB apart).
// r19's gemmF (f32-direct staging) abandoned: 4.19M bank conflicts, 4th
// failed derived swizzle.
// ws (MiB): XF@0(48) WT@48(6) PROJ@54(32: K,Q) VTb@86(16) SC@102(32,f16)
//           P@0(32, alias XF dead post-proj). high-water 134 MiB.
// ---------------------------------------------------------------------------

typedef __attribute__((ext_vector_type(4))) float    f32x4;
typedef __attribute__((ext_vector_type(8))) _Float16 f16x8;
typedef __attribute__((ext_vector_type(4))) _Float16 f16x4;

constexpr size_t MiB = 1u << 20;
constexpr size_t MK  = (size_t)8192 * 1024;
constexpr size_t WSZ = (size_t)1024 * 1024;

__device__ __forceinline__ void gload_lds16(const void* g, void* l) {
  __builtin_amdgcn_global_load_lds(
      (const __attribute__((address_space(1))) unsigned int*)g,
      (__attribute__((address_space(3))) unsigned int*)l, 16, 0, 0);
}

#define MFMA16(a, b, c) __builtin_amdgcn_mfma_f32_16x16x32_f16(a, b, c, 0, 0, 0)

// XCD-chunked bijective block swizzle (requires total blocks % 8 == 0).
__device__ __forceinline__ void swz_block(int& bx, int& by, int& bz) {
  unsigned gx = gridDim.x, gy = gridDim.y;
  unsigned flat = blockIdx.x + gx * (blockIdx.y + gy * blockIdx.z);
  unsigned total = gx * gy * gridDim.z;
  unsigned cpx = total >> 3;
  unsigned s = (flat & 7) * cpx + (flat >> 3);
  bx = s % gx; s /= gx; by = s % gy; bz = s / gy;
}

// ---------------------------------------------------------------------------
// prep (r18-measured): ids 0..767 = W->W^T (64x64 tiles, FIRST);
// ids 768..6911 = X->f16 (hoisted NT loads/stores).
__global__ __launch_bounds__(256) void prep(
    const float* __restrict__ x0, const float* __restrict__ x1,
    const float* __restrict__ x2, _Float16* __restrict__ XF,
    const float* __restrict__ w0, const float* __restrict__ w1,
    const float* __restrict__ w2, _Float16* __restrict__ WT)
{
  const unsigned id = blockIdx.x;
  const int tid = threadIdx.x;
  if (id < 768) {
    const int z = id >> 8;
    const unsigned blk = id & 255;
    const float* W = z == 0 ? w0 : (z == 1 ? w1 : w2);
    _Float16* o = WT + (size_t)z * WSZ;
    __shared__ float tile[64][65];
    const int bx = (blk & 15) * 64;      // n
    const int by = (blk >> 4) * 64;      // k
    const int tx = tid & 15, ty = tid >> 4;
    #pragma unroll
    for (int p = 0; p < 4; ++p) {
      f32x4 v = *(const f32x4*)(&W[(size_t)(by + ty + 16 * p) * 1024 + bx + 4 * tx]);
      tile[ty + 16 * p][4 * tx + 0] = v.x;
      tile[ty + 16 * p][4 * tx + 1] = v.y;
      tile[ty + 16 * p][4 * tx + 2] = v.z;
      tile[ty + 16 * p][4 * tx + 3] = v.w;
    }
    __syncthreads();
    const int rr = tid >> 3, cc = tid & 7;
    #pragma unroll
    for (int q = 0; q < 2; ++q) {
      const int nl = rr + 32 * q;
      f16x8 h;
      #pragma unroll
      for (int j = 0; j < 8; ++j) h[j] = (_Float16)tile[8 * cc + j][nl];
      *(f16x8*)(&o[(size_t)(bx + nl) * 1024 + by + 8 * cc]) = h;
    }
  } else {
    const unsigned idx = id - 768;
    const int z = idx >> 11;
    const unsigned blk = idx & 2047;
    const float* x = (z == 0 ? x0 : (z == 1 ? x1 : x2)) + (size_t)blk * 4096;
    _Float16* o = XF + (size_t)z * MK + (size_t)blk * 4096;
    const int t4 = tid * 4;
    const f32x4* p0 = (const f32x4*)(x + t4);
    const f32x4* p1 = (const f32x4*)(x + 1024 + t4);
    const f32x4* p2 = (const f32x4*)(x + 2048 + t4);
    const f32x4* p3 = (const f32x4*)(x + 3072 + t4);
    f32x4 a0 = __builtin_nontemporal_load(p0);
    f32x4 a1 = __builtin_nontemporal_load(p1);
    f32x4 a2 = __builtin_nontemporal_load(p2);
    f32x4 a3 = __builtin_nontemporal_load(p3);
    f16x4 h0 = {(_Float16)a0.x, (_Float16)a0.y, (_Float16)a0.z, (_Float16)a0.w};
    f16x4 h1 = {(_Float16)a1.x, (_Float16)a1.y, (_Float16)a1.z, (_Float16)a1.w};
    f16x4 h2 = {(_Float16)a2.x, (_Float16)a2.y, (_Float16)a2.z, (_Float16)a2.w};
    f16x4 h3 = {(_Float16)a3.x, (_Float16)a3.y, (_Float16)a3.z, (_Float16)a3.w};
    __builtin_nontemporal_store(h0, (f16x4*)(o + t4));
    __builtin_nontemporal_store(h1, (f16x4*)(o + 1024 + t4));
    __builtin_nontemporal_store(h2, (f16x4*)(o + 2048 + t4));
    __builtin_nontemporal_store(h3, (f16x4*)(o + 3072 + t4));
  }
}

// ---------------------------------------------------------------------------
// gemm8p (r7 verbatim): 256x256 BK=64, 4 phases/K-tile, counted vmcnt(2).
// MODE 1: f16 ; 2: f16*scale.
template <int MODE>
__global__ __launch_bounds__(512, 2) void gemm8p(
    const _Float16* __restrict__ At, size_t sA,
    const _Float16* __restrict__ Bt, size_t sB,
    void* __restrict__ Cv, size_t sCz,
    int N, int K, float scale)
{
  extern __shared__ char lds[];
  int bx, by, bz;
  swz_block(bx, by, bz);
  const _Float16* A = At + (size_t)bz * sA;
  const _Float16* B = Bt + (size_t)bz * sB;

  const int gm0 = by * 256, gn0 = bx * 256;
  const int tid = threadIdx.x;
  const int lane = tid & 63, wave = tid >> 6;
  const int wm = (wave >> 2) * 128;
  const int wn = (wave & 3) * 64;
  const int fr = lane & 15, fq = lane >> 4;
  const int nkt = K >> 6;

  const int clog = ((tid & 7) ^ ((tid >> 3) & 7)) * 8;
  const _Float16* srcA = A + (size_t)(gm0 + (tid >> 3)) * K + clog;
  const _Float16* srcB = B + (size_t)(gn0 + (tid >> 3)) * K + clog;
  char* const dst0 = lds + tid * 16;

  auto SH = [&](int tile, int h) {
    const _Float16* s = (h < 2 ? srcA : srcB) + (size_t)((h & 1) * 128) * K
                        + tile * 64;
    char* d = dst0 + (tile & 1) * 65536 + h * 16384;
    gload_lds16(s, d);
    gload_lds16(s + (size_t)64 * K, d + 8192);
  };

  const int axor = fr & 7;
  const int pc0 = (fq ^ axor) * 16;
  const int pc1 = ((4 + fq) ^ axor) * 16;
  const int arb = (wm + fr) * 128;
  const int brb = 32768 + (wn + fr) * 128;

  f32x4 acc[8][4] = {};
  f16x8 af[4][2], b0[2][2], b1[2][2];

  SH(0, 0); SH(0, 1); SH(0, 2); SH(0, 3);
  if (nkt > 1) {
    SH(1, 0);
    asm volatile("s_waitcnt vmcnt(2)" ::: "memory");
  } else {
    asm volatile("s_waitcnt vmcnt(0)" ::: "memory");
  }
  __builtin_amdgcn_s_barrier();
  __builtin_amdgcn_sched_barrier(0);

#define PHASE_MID                                          \
  __builtin_amdgcn_s_barrier();                            \
  asm volatile("s_waitcnt lgkmcnt(0)" ::: "memory");       \
  __builtin_amdgcn_sched_barrier(0);                       \
  __builtin_amdgcn_s_setprio(1);
#define PHASE_END                                          \
  __builtin_amdgcn_s_setprio(0);                           \
  __builtin_amdgcn_sched_barrier(0);                       \
  __builtin_amdgcn_s_barrier();

  for (int t = 0; t < nkt; ++t) {
    const char* buf = lds + (t & 1) * 65536;
    const bool st1 = (t + 1) < nkt;

    #pragma unroll
    for (int mi = 0; mi < 4; ++mi) {
      af[mi][0] = *(const f16x8*)(buf + arb + mi * 2048 + pc0);
      af[mi][1] = *(const f16x8*)(buf + arb + mi * 2048 + pc1);
    }
    #pragma unroll
    for (int ni = 0; ni < 2; ++ni) {
      b0[ni][0] = *(const f16x8*)(buf + brb + ni * 2048 + pc0);
      b0[ni][1] = *(const f16x8*)(buf + brb + ni * 2048 + pc1);
    }
    if (st1) SH(t + 1, 1);
    PHASE_MID
    #pragma unroll
    for (int mi = 0; mi < 4; ++mi)
      #pragma unroll
      for (int ni = 0; ni < 2; ++ni)
        #pragma unroll
        for (int kk = 0; kk < 2; ++kk)
          acc[mi][ni] = MFMA16(af[mi][kk], b0[ni][kk], acc[mi][ni]);
    PHASE_END

    #pragma unroll
    for (int ni = 0; ni < 2; ++ni) {
      b1[ni][0] = *(const f16x8*)(buf + brb + (ni + 2) * 2048 + pc0);
      b1[ni][1] = *(const f16x8*)(buf + brb + (ni + 2) * 2048 + pc1);
    }
    if (st1) SH(t + 1, 2);
    PHASE_MID
    #pragma unroll
    for (int mi = 0; mi < 4; ++mi)
      #pragma unroll
      for (int ni = 0; ni < 2; ++ni)
        #pragma unroll
        for (int kk = 0; kk < 2; ++kk)
          acc[mi][ni + 2] = MFMA16(af[mi][kk], b1[ni][kk], acc[mi][ni + 2]);
    PHASE_END

    #pragma unroll
    for (int mi = 0; mi < 4; ++mi) {
      af[mi][0] = *(const f16x8*)(buf + arb + (mi + 4) * 2048 + pc0);
      af[mi][1] = *(const f16x8*)(buf + arb + (mi + 4) * 2048 + pc1);
    }
    if (st1) SH(t + 1, 3);
    PHASE_MID
    #pragma unroll
    for (int mi = 0; mi < 4; ++mi)
      #pragma unroll
      for (int ni = 0; ni < 2; ++ni)
        #pragma unroll
        for (int kk = 0; kk < 2; ++kk)
          acc[mi + 4][ni] = MFMA16(af[mi][kk], b0[ni][kk], acc[mi + 4][ni]);
    PHASE_END

    const bool st2 = (t + 2) < nkt;
    if (st2) SH(t + 2, 0);
    __builtin_amdgcn_s_barrier();
    __builtin_amdgcn_s_setprio(1);
    #pragma unroll
    for (int mi = 0; mi < 4; ++mi)
      #pragma unroll
      for (int ni = 0; ni < 2; ++ni)
        #pragma unroll
        for (int kk = 0; kk < 2; ++kk)
          acc[mi + 4][ni + 2] = MFMA16(af[mi][kk], b1[ni][kk], acc[mi + 4][ni + 2]);
    __builtin_amdgcn_s_setprio(0);
    __builtin_amdgcn_sched_barrier(0);
    if (st2) asm volatile("s_waitcnt vmcnt(2)" ::: "memory");
    else     asm volatile("s_waitcnt vmcnt(0)" ::: "memory");
    __builtin_amdgcn_s_barrier();
  }
#undef PHASE_MID
#undef PHASE_END

  const int erow = gm0 + wm + fq * 4;
  const int ecol = gn0 + wn + fr;
  #pragma unroll
  for (int m = 0; m < 8; ++m)
    #pragma unroll
    for (int n = 0; n < 4; ++n) {
      size_t base = (size_t)(erow + m * 16) * N + (ecol + n * 16);
      #pragma unroll
      for (int r = 0; r < 4; ++r) {
        float v = acc[m][n][r];
        if constexpr (MODE == 1)
          ((_Float16*)Cv + (size_t)bz * sCz)[base + (size_t)r * N] = (_Float16)v;
        else
          ((_Float16*)Cv + (size_t)bz * sCz)[base + (size_t)r * N] =
              (_Float16)(v * scale);
      }
    }
}

// ---------------------------------------------------------------------------
// gemmO (r14 verbatim): 256x128, BK=32, 3-deep, 72KiB, lda/ldb/ldc.
// MODE 0: f32*scale ; 1: f16.
template <int MODE>
__global__ __launch_bounds__(512, 4) void gemmO(
    const _Float16* __restrict__ At, size_t sAz, int lda,
    const _Float16* __restrict__ Bt, size_t sBz, int ldb,
    void* __restrict__ Cv, size_t sCz, int ldc,
    int K, float scale)
{
  extern __shared__ char lds[];
  int bx, by, bz;
  swz_block(bx, by, bz);
  const _Float16* A = At + (size_t)bz * sAz;
  const _Float16* B = Bt + (size_t)bz * sBz;

  const int gm0 = by * 256, gn0 = bx * 128;
  const int tid = threadIdx.x;
  const int lane = tid & 63, wave = tid >> 6;
  const int wm = (wave >> 1) * 64;
  const int wn = (wave & 1) * 64;
  const int fr = lane & 15, fq = lane >> 4;
  const int nkt = K >> 5;

  const int clog = ((tid & 3) ^ ((tid >> 3) & 3)) * 8;
  const _Float16* srcA = A + (size_t)(gm0 + (tid >> 2)) * lda + clog;
  const _Float16* srcB = B + (size_t)(gn0 + (tid >> 2)) * ldb + clog;
  char* const dst0 = lds + tid * 16;

  auto STG = [&](int tile) {
    const int off = tile * 32;
    char* d = dst0 + (tile % 3) * 24576;
    gload_lds16(srcA + off,                     d);
    gload_lds16(srcA + off + (size_t)128 * lda, d + 8192);
    gload_lds16(srcB + off,                     d + 16384);
  };

  const int pc  = (fq ^ ((fr >> 1) & 3)) * 16;
  const int arb = (wm + fr) * 64 + pc;
  const int brb = 16384 + (wn + fr) * 64 + pc;

  f32x4 acc[4][4] = {};
  f16x8 af[4], bfr[4];

  STG(0);
  if (nkt > 1) {
    STG(1);
    asm volatile("s_waitcnt vmcnt(3)" ::: "memory");
  } else {
    asm volatile("s_waitcnt vmcnt(0)" ::: "memory");
  }
  __builtin_amdgcn_s_barrier();
  __builtin_amdgcn_sched_barrier(0);

  for (int t = 0; t < nkt; ++t) {
    const char* buf = lds + (t % 3) * 24576;
    const bool st2 = (t + 2) < nkt;

    if (st2) STG(t + 2);

    #pragma unroll
    for (int mi = 0; mi < 4; ++mi)
      af[mi] = *(const f16x8*)(buf + arb + mi * 1024);
    #pragma unroll
    for (int ni = 0; ni < 4; ++ni)
      bfr[ni] = *(const f16x8*)(buf + brb + ni * 1024);

    __builtin_amdgcn_s_setprio(1);
    #pragma unroll
    for (int mi = 0; mi < 4; ++mi)
      #pragma unroll
      for (int ni = 0; ni < 4; ++ni)
        acc[mi][ni] = MFMA16(af[mi], bfr[ni], acc[mi][ni]);
    __builtin_amdgcn_s_setprio(0);

    if (st2)               asm volatile("s_waitcnt vmcnt(3)" ::: "memory");
    else if (t + 1 < nkt)  asm volatile("s_waitcnt vmcnt(0)" ::: "memory");
    __builtin_amdgcn_s_barrier();
    __builtin_amdgcn_sched_barrier(0);
  }

  const int erow = gm0 + wm + fq * 4;
  const int ecol = gn0 + wn + fr;
  #pragma unroll
  for (int m = 0; m < 4; ++m)
    #pragma unroll
    for (int n = 0; n < 4; ++n) {
      size_t base = (size_t)(erow + m * 16) * ldc + (ecol + n * 16);
      #pragma unroll
      for (int r = 0; r < 4; ++r) {
        float v = acc[m][n][r];
        size_t idx = base + (size_t)r * ldc;
        if constexpr (MODE == 0)
          ((float*)Cv + (size_t)bz * sCz)[idx] = v * scale;
        else
          ((_Float16*)Cv + (size_t)bz * sCz)[idx] = (_Float16)v;
      }
    }
}

// ---------------------------------------------------------------------------
// Wave-per-row softmax: scores [8192 rows][2048] f16 -> P f16. 8 rows/block.
__global__ __launch_bounds__(512) void softmax_rows(
    const _Float16* __restrict__ S, _Float16* __restrict__ P)
{
  const int w = threadIdx.x >> 6, lane = threadIdx.x & 63;
  const size_t row = (size_t)blockIdx.x * 8 + w;
  const _Float16* sr = S + row * 2048;

  f16x8 v[4];
  #pragma unroll
  for (int c = 0; c < 4; ++c)
    v[c] = *(const f16x8*)(sr + c * 512 + lane * 8);

  float m = -1e30f;
  #pragma unroll
  for (int c = 0; c < 4; ++c)
    #pragma unroll
    for (int j = 0; j < 8; ++j) m = fmaxf(m, (float)v[c][j]);
  #pragma unroll
  for (int o = 32; o >= 1; o >>= 1) m = fmaxf(m, __shfl_xor(m, o));

  float e[4][8];
  float s = 0.f;
  #pragma unroll
  for (int c = 0; c < 4; ++c)
    #pragma unroll
    for (int j = 0; j < 8; ++j) {
      e[c][j] = __expf((float)v[c][j] - m);
      s += e[c][j];
    }
  #pragma unroll
  for (int o = 32; o >= 1; o >>= 1) s += __shfl_xor(s, o);

  const float inv = 1.0f / s;
  _Float16* pr = P + row * 2048;
  #pragma unroll
  for (int c = 0; c < 4; ++c) {
    f16x8 p;
    #pragma unroll
    for (int j = 0; j < 8; ++j) p[j] = (_Float16)(e[c][j] * inv);
    *(f16x8*)(pr + c * 512 + lane * 8) = p;
  }
}

// ---------------------------------------------------------------------------
extern "C" void kernel_launch(void* const* d_in, const int* in_sizes, int n_in,
                              void* d_out, int out_size, void* d_ws, size_t ws_size,
                              hipStream_t stream)
{
  const float* Xk = (const float*)d_in[0];
  const float* Xv = (const float*)d_in[1];
  const float* Xq = (const float*)d_in[2];
  const float* WK = (const float*)d_in[3];
  const float* WV = (const float*)d_in[4];
  const float* WQ = (const float*)d_in[5];
  float* out = (float*)d_out;
  char* ws = (char*)d_ws;

  _Float16* XF   = (_Float16*)(ws);               // 0..48 MiB (k,v,q)
  _Float16* WT   = (_Float16*)(ws + 48 * MiB);    // 48..54 (K,V,Q)
  _Float16* PROJ = (_Float16*)(ws + 54 * MiB);    // 54..86 (K,Q)
  _Float16* VTb  = (_Float16*)(ws + 86 * MiB);    // 86..102 [4][1024][2048]
  _Float16* SC   = (_Float16*)(ws + 102 * MiB);   // 102..134 (f16 scores)
  _Float16* P    = (_Float16*)(ws);               // alias XF (dead post-proj)

  _Float16* Kp = PROJ;            // [8192][1024]
  _Float16* Qp = PROJ + MK;       // [8192][1024]

  auto* g1 = gemm8p<1>;
  auto* g2 = gemm8p<2>;
  auto* f1 = gemmO<1>;
  auto* f0 = gemmO<0>;
  (void)hipFuncSetAttribute((const void*)g1, hipFuncAttributeMaxDynamicSharedMemorySize, 131072);
  (void)hipFuncSetAttribute((const void*)g2, hipFuncAttributeMaxDynamicSharedMemorySize, 131072);
  (void)hipFuncSetAttribute((const void*)f1, hipFuncAttributeMaxDynamicSharedMemorySize, 73728);
  (void)hipFuncSetAttribute((const void*)f0, hipFuncAttributeMaxDynamicSharedMemorySize, 73728);

  // 1) prep: W^T tiles first (tail-hidden), then X -> f16 (hoisted + NT)
  prep<<<dim3(6912), 256, 0, stream>>>(Xk, Xv, Xq, XF, WK, WV, WQ, WT);
  // 2) K,Q projections on gemm8p: (4,32,2) = 256 blocks = 1.0 round
  gemm8p<1><<<dim3(4, 32, 2), 512, 131072, stream>>>(
      XF, 2 * MK, WT, 2 * WSZ, PROJ, MK, 1024, 1024, 1.0f);
  // 3) V^T projection, PER-BATCH contiguous: VTb[b][e][s] = sum_k
  //    WT_V[e][k] * XF_v[b*2048+s][k].  grid (16,4,4) = 256 blocks.
  gemmO<1><<<dim3(16, 4, 4), 512, 73728, stream>>>(
      WT + WSZ, 0, 1024, XF + MK, (size_t)2048 * 1024, 1024,
      VTb, (size_t)1024 * 2048, 2048, 1024, 1.0f);
  // 4) scores[b] = Q[b]@K[b]^T / sqrt(2048) -> f16  (256 blocks)
  gemm8p<2><<<dim3(8, 8, 4), 512, 131072, stream>>>(
      Qp, (size_t)2048 * 1024, Kp, (size_t)2048 * 1024,
      SC, (size_t)2048 * 2048, 2048, 1024, 0.022097086912079608f);
  // 5) softmax (wave-per-row, 8 rows/block) -> P f16
  softmax_rows<<<dim3(1024), 512, 0, stream>>>(SC, P);
  // 6) out[b] = P[b] @ V[b]: B = VTb[b] contiguous ldb=2048
  gemmO<0><<<dim3(8, 8, 4), 512, 73728, stream>>>(
      P, (size_t)2048 * 2048, 2048, VTb, (size_t)1024 * 2048, 2048,
      out, (size_t)2048 * 1024, 1024, 2048, 1.0f);
}

// Round 21
// 184.086 us; speedup vs baseline: 1.0334x; 1.0111x over previous
//
#include <hip/hip_runtime.h>
#include <hip/hip_bf16.h>

// ---------------------------------------------------------------------------
// AttentionHead B=4,S=2048,D=1024 — round 21 (final stabilization).
// = r20 with ONE fix: removed __builtin_nontemporal_store on XF (XF is
// re-read by the proj GEMMs; NT stores evicted it from L2 — the consistent
// ~3us r15-vs-r18/r20 delta). NT loads kept (X is read exactly once).
// ws (MiB): XF@0(48) WT@48(6) PROJ@54(32: K,Q) VTb@86(16) SC@102(32,f16)
//           P@0(32, alias XF dead post-proj). high-water 134 MiB.
// ---------------------------------------------------------------------------

typedef __attribute__((ext_vector_type(4))) float    f32x4;
typedef __attribute__((ext_vector_type(8))) _Float16 f16x8;
typedef __attribute__((ext_vector_type(4))) _Float16 f16x4;

constexpr size_t MiB = 1u << 20;
constexpr size_t MK  = (size_t)8192 * 1024;
constexpr size_t WSZ = (size_t)1024 * 1024;

__device__ __forceinline__ void gload_lds16(const void* g, void* l) {
  __builtin_amdgcn_global_load_lds(
      (const __attribute__((address_space(1))) unsigned int*)g,
      (__attribute__((address_space(3))) unsigned int*)l, 16, 0, 0);
}

#define MFMA16(a, b, c) __builtin_amdgcn_mfma_f32_16x16x32_f16(a, b, c, 0, 0, 0)

// XCD-chunked bijective block swizzle (requires total blocks % 8 == 0).
__device__ __forceinline__ void swz_block(int& bx, int& by, int& bz) {
  unsigned gx = gridDim.x, gy = gridDim.y;
  unsigned flat = blockIdx.x + gx * (blockIdx.y + gy * blockIdx.z);
  unsigned total = gx * gy * gridDim.z;
  unsigned cpx = total >> 3;
  unsigned s = (flat & 7) * cpx + (flat >> 3);
  bx = s % gx; s /= gx; by = s % gy; bz = s / gy;
}

// ---------------------------------------------------------------------------
// prep: ids 0..767 = W->W^T (64x64 tiles, FIRST);
// ids 768..6911 = X->f16 (hoisted NT loads, REGULAR stores).
__global__ __launch_bounds__(256) void prep(
    const float* __restrict__ x0, const float* __restrict__ x1,
    const float* __restrict__ x2, _Float16* __restrict__ XF,
    const float* __restrict__ w0, const float* __restrict__ w1,
    const float* __restrict__ w2, _Float16* __restrict__ WT)
{
  const unsigned id = blockIdx.x;
  const int tid = threadIdx.x;
  if (id < 768) {
    const int z = id >> 8;
    const unsigned blk = id & 255;
    const float* W = z == 0 ? w0 : (z == 1 ? w1 : w2);
    _Float16* o = WT + (size_t)z * WSZ;
    __shared__ float tile[64][65];
    const int bx = (blk & 15) * 64;      // n
    const int by = (blk >> 4) * 64;      // k
    const int tx = tid & 15, ty = tid >> 4;
    #pragma unroll
    for (int p = 0; p < 4; ++p) {
      f32x4 v = *(const f32x4*)(&W[(size_t)(by + ty + 16 * p) * 1024 + bx + 4 * tx]);
      tile[ty + 16 * p][4 * tx + 0] = v.x;
      tile[ty + 16 * p][4 * tx + 1] = v.y;
      tile[ty + 16 * p][4 * tx + 2] = v.z;
      tile[ty + 16 * p][4 * tx + 3] = v.w;
    }
    __syncthreads();
    const int rr = tid >> 3, cc = tid & 7;
    #pragma unroll
    for (int q = 0; q < 2; ++q) {
      const int nl = rr + 32 * q;
      f16x8 h;
      #pragma unroll
      for (int j = 0; j < 8; ++j) h[j] = (_Float16)tile[8 * cc + j][nl];
      *(f16x8*)(&o[(size_t)(bx + nl) * 1024 + by + 8 * cc]) = h;
    }
  } else {
    const unsigned idx = id - 768;
    const int z = idx >> 11;
    const unsigned blk = idx & 2047;
    const float* x = (z == 0 ? x0 : (z == 1 ? x1 : x2)) + (size_t)blk * 4096;
    _Float16* o = XF + (size_t)z * MK + (size_t)blk * 4096;
    const int t4 = tid * 4;
    const f32x4* p0 = (const f32x4*)(x + t4);
    const f32x4* p1 = (const f32x4*)(x + 1024 + t4);
    const f32x4* p2 = (const f32x4*)(x + 2048 + t4);
    const f32x4* p3 = (const f32x4*)(x + 3072 + t4);
    f32x4 a0 = __builtin_nontemporal_load(p0);
    f32x4 a1 = __builtin_nontemporal_load(p1);
    f32x4 a2 = __builtin_nontemporal_load(p2);
    f32x4 a3 = __builtin_nontemporal_load(p3);
    f16x4 h0 = {(_Float16)a0.x, (_Float16)a0.y, (_Float16)a0.z, (_Float16)a0.w};
    f16x4 h1 = {(_Float16)a1.x, (_Float16)a1.y, (_Float16)a1.z, (_Float16)a1.w};
    f16x4 h2 = {(_Float16)a2.x, (_Float16)a2.y, (_Float16)a2.z, (_Float16)a2.w};
    f16x4 h3 = {(_Float16)a3.x, (_Float16)a3.y, (_Float16)a3.z, (_Float16)a3.w};
    *(f16x4*)(o + t4)        = h0;   // regular stores: XF is re-read by GEMMs
    *(f16x4*)(o + 1024 + t4) = h1;
    *(f16x4*)(o + 2048 + t4) = h2;
    *(f16x4*)(o + 3072 + t4) = h3;
  }
}

// ---------------------------------------------------------------------------
// gemm8p (r7 verbatim): 256x256 BK=64, 4 phases/K-tile, counted vmcnt(2).
// MODE 1: f16 ; 2: f16*scale.
template <int MODE>
__global__ __launch_bounds__(512, 2) void gemm8p(
    const _Float16* __restrict__ At, size_t sA,
    const _Float16* __restrict__ Bt, size_t sB,
    void* __restrict__ Cv, size_t sCz,
    int N, int K, float scale)
{
  extern __shared__ char lds[];
  int bx, by, bz;
  swz_block(bx, by, bz);
  const _Float16* A = At + (size_t)bz * sA;
  const _Float16* B = Bt + (size_t)bz * sB;

  const int gm0 = by * 256, gn0 = bx * 256;
  const int tid = threadIdx.x;
  const int lane = tid & 63, wave = tid >> 6;
  const int wm = (wave >> 2) * 128;
  const int wn = (wave & 3) * 64;
  const int fr = lane & 15, fq = lane >> 4;
  const int nkt = K >> 6;

  const int clog = ((tid & 7) ^ ((tid >> 3) & 7)) * 8;
  const _Float16* srcA = A + (size_t)(gm0 + (tid >> 3)) * K + clog;
  const _Float16* srcB = B + (size_t)(gn0 + (tid >> 3)) * K + clog;
  char* const dst0 = lds + tid * 16;

  auto SH = [&](int tile, int h) {
    const _Float16* s = (h < 2 ? srcA : srcB) + (size_t)((h & 1) * 128) * K
                        + tile * 64;
    char* d = dst0 + (tile & 1) * 65536 + h * 16384;
    gload_lds16(s, d);
    gload_lds16(s + (size_t)64 * K, d + 8192);
  };

  const int axor = fr & 7;
  const int pc0 = (fq ^ axor) * 16;
  const int pc1 = ((4 + fq) ^ axor) * 16;
  const int arb = (wm + fr) * 128;
  const int brb = 32768 + (wn + fr) * 128;

  f32x4 acc[8][4] = {};
  f16x8 af[4][2], b0[2][2], b1[2][2];

  SH(0, 0); SH(0, 1); SH(0, 2); SH(0, 3);
  if (nkt > 1) {
    SH(1, 0);
    asm volatile("s_waitcnt vmcnt(2)" ::: "memory");
  } else {
    asm volatile("s_waitcnt vmcnt(0)" ::: "memory");
  }
  __builtin_amdgcn_s_barrier();
  __builtin_amdgcn_sched_barrier(0);

#define PHASE_MID                                          \
  __builtin_amdgcn_s_barrier();                            \
  asm volatile("s_waitcnt lgkmcnt(0)" ::: "memory");       \
  __builtin_amdgcn_sched_barrier(0);                       \
  __builtin_amdgcn_s_setprio(1);
#define PHASE_END                                          \
  __builtin_amdgcn_s_setprio(0);                           \
  __builtin_amdgcn_sched_barrier(0);                       \
  __builtin_amdgcn_s_barrier();

  for (int t = 0; t < nkt; ++t) {
    const char* buf = lds + (t & 1) * 65536;
    const bool st1 = (t + 1) < nkt;

    #pragma unroll
    for (int mi = 0; mi < 4; ++mi) {
      af[mi][0] = *(const f16x8*)(buf + arb + mi * 2048 + pc0);
      af[mi][1] = *(const f16x8*)(buf + arb + mi * 2048 + pc1);
    }
    #pragma unroll
    for (int ni = 0; ni < 2; ++ni) {
      b0[ni][0] = *(const f16x8*)(buf + brb + ni * 2048 + pc0);
      b0[ni][1] = *(const f16x8*)(buf + brb + ni * 2048 + pc1);
    }
    if (st1) SH(t + 1, 1);
    PHASE_MID
    #pragma unroll
    for (int mi = 0; mi < 4; ++mi)
      #pragma unroll
      for (int ni = 0; ni < 2; ++ni)
        #pragma unroll
        for (int kk = 0; kk < 2; ++kk)
          acc[mi][ni] = MFMA16(af[mi][kk], b0[ni][kk], acc[mi][ni]);
    PHASE_END

    #pragma unroll
    for (int ni = 0; ni < 2; ++ni) {
      b1[ni][0] = *(const f16x8*)(buf + brb + (ni + 2) * 2048 + pc0);
      b1[ni][1] = *(const f16x8*)(buf + brb + (ni + 2) * 2048 + pc1);
    }
    if (st1) SH(t + 1, 2);
    PHASE_MID
    #pragma unroll
    for (int mi = 0; mi < 4; ++mi)
      #pragma unroll
      for (int ni = 0; ni < 2; ++ni)
        #pragma unroll
        for (int kk = 0; kk < 2; ++kk)
          acc[mi][ni + 2] = MFMA16(af[mi][kk], b1[ni][kk], acc[mi][ni + 2]);
    PHASE_END

    #pragma unroll
    for (int mi = 0; mi < 4; ++mi) {
      af[mi][0] = *(const f16x8*)(buf + arb + (mi + 4) * 2048 + pc0);
      af[mi][1] = *(const f16x8*)(buf + arb + (mi + 4) * 2048 + pc1);
    }
    if (st1) SH(t + 1, 3);
    PHASE_MID
    #pragma unroll
    for (int mi = 0; mi < 4; ++mi)
      #pragma unroll
      for (int ni = 0; ni < 2; ++ni)
        #pragma unroll
        for (int kk = 0; kk < 2; ++kk)
          acc[mi + 4][ni] = MFMA16(af[mi][kk], b0[ni][kk], acc[mi + 4][ni]);
    PHASE_END

    const bool st2 = (t + 2) < nkt;
    if (st2) SH(t + 2, 0);
    __builtin_amdgcn_s_barrier();
    __builtin_amdgcn_s_setprio(1);
    #pragma unroll
    for (int mi = 0; mi < 4; ++mi)
      #pragma unroll
      for (int ni = 0; ni < 2; ++ni)
        #pragma unroll
        for (int kk = 0; kk < 2; ++kk)
          acc[mi + 4][ni + 2] = MFMA16(af[mi][kk], b1[ni][kk], acc[mi + 4][ni + 2]);
    __builtin_amdgcn_s_setprio(0);
    __builtin_amdgcn_sched_barrier(0);
    if (st2) asm volatile("s_waitcnt vmcnt(2)" ::: "memory");
    else     asm volatile("s_waitcnt vmcnt(0)" ::: "memory");
    __builtin_amdgcn_s_barrier();
  }
#undef PHASE_MID
#undef PHASE_END

  const int erow = gm0 + wm + fq * 4;
  const int ecol = gn0 + wn + fr;
  #pragma unroll
  for (int m = 0; m < 8; ++m)
    #pragma unroll
    for (int n = 0; n < 4; ++n) {
      size_t base = (size_t)(erow + m * 16) * N + (ecol + n * 16);
      #pragma unroll
      for (int r = 0; r < 4; ++r) {
        float v = acc[m][n][r];
        if constexpr (MODE == 1)
          ((_Float16*)Cv + (size_t)bz * sCz)[base + (size_t)r * N] = (_Float16)v;
        else
          ((_Float16*)Cv + (size_t)bz * sCz)[base + (size_t)r * N] =
              (_Float16)(v * scale);
      }
    }
}

// ---------------------------------------------------------------------------
// gemmO (r14 verbatim): 256x128, BK=32, 3-deep, 72KiB, lda/ldb/ldc.
// MODE 0: f32*scale ; 1: f16.
template <int MODE>
__global__ __launch_bounds__(512, 4) void gemmO(
    const _Float16* __restrict__ At, size_t sAz, int lda,
    const _Float16* __restrict__ Bt, size_t sBz, int ldb,
    void* __restrict__ Cv, size_t sCz, int ldc,
    int K, float scale)
{
  extern __shared__ char lds[];
  int bx, by, bz;
  swz_block(bx, by, bz);
  const _Float16* A = At + (size_t)bz * sAz;
  const _Float16* B = Bt + (size_t)bz * sBz;

  const int gm0 = by * 256, gn0 = bx * 128;
  const int tid = threadIdx.x;
  const int lane = tid & 63, wave = tid >> 6;
  const int wm = (wave >> 1) * 64;
  const int wn = (wave & 1) * 64;
  const int fr = lane & 15, fq = lane >> 4;
  const int nkt = K >> 5;

  const int clog = ((tid & 3) ^ ((tid >> 3) & 3)) * 8;
  const _Float16* srcA = A + (size_t)(gm0 + (tid >> 2)) * lda + clog;
  const _Float16* srcB = B + (size_t)(gn0 + (tid >> 2)) * ldb + clog;
  char* const dst0 = lds + tid * 16;

  auto STG = [&](int tile) {
    const int off = tile * 32;
    char* d = dst0 + (tile % 3) * 24576;
    gload_lds16(srcA + off,                     d);
    gload_lds16(srcA + off + (size_t)128 * lda, d + 8192);
    gload_lds16(srcB + off,                     d + 16384);
  };

  const int pc  = (fq ^ ((fr >> 1) & 3)) * 16;
  const int arb = (wm + fr) * 64 + pc;
  const int brb = 16384 + (wn + fr) * 64 + pc;

  f32x4 acc[4][4] = {};
  f16x8 af[4], bfr[4];

  STG(0);
  if (nkt > 1) {
    STG(1);
    asm volatile("s_waitcnt vmcnt(3)" ::: "memory");
  } else {
    asm volatile("s_waitcnt vmcnt(0)" ::: "memory");
  }
  __builtin_amdgcn_s_barrier();
  __builtin_amdgcn_sched_barrier(0);

  for (int t = 0; t < nkt; ++t) {
    const char* buf = lds + (t % 3) * 24576;
    const bool st2 = (t + 2) < nkt;

    if (st2) STG(t + 2);

    #pragma unroll
    for (int mi = 0; mi < 4; ++mi)
      af[mi] = *(const f16x8*)(buf + arb + mi * 1024);
    #pragma unroll
    for (int ni = 0; ni < 4; ++ni)
      bfr[ni] = *(const f16x8*)(buf + brb + ni * 1024);

    __builtin_amdgcn_s_setprio(1);
    #pragma unroll
    for (int mi = 0; mi < 4; ++mi)
      #pragma unroll
      for (int ni = 0; ni < 4; ++ni)
        acc[mi][ni] = MFMA16(af[mi], bfr[ni], acc[mi][ni]);
    __builtin_amdgcn_s_setprio(0);

    if (st2)               asm volatile("s_waitcnt vmcnt(3)" ::: "memory");
    else if (t + 1 < nkt)  asm volatile("s_waitcnt vmcnt(0)" ::: "memory");
    __builtin_amdgcn_s_barrier();
    __builtin_amdgcn_sched_barrier(0);
  }

  const int erow = gm0 + wm + fq * 4;
  const int ecol = gn0 + wn + fr;
  #pragma unroll
  for (int m = 0; m < 4; ++m)
    #pragma unroll
    for (int n = 0; n < 4; ++n) {
      size_t base = (size_t)(erow + m * 16) * ldc + (ecol + n * 16);
      #pragma unroll
      for (int r = 0; r < 4; ++r) {
        float v = acc[m][n][r];
        size_t idx = base + (size_t)r * ldc;
        if constexpr (MODE == 0)
          ((float*)Cv + (size_t)bz * sCz)[idx] = v * scale;
        else
          ((_Float16*)Cv + (size_t)bz * sCz)[idx] = (_Float16)v;
      }
    }
}

// ---------------------------------------------------------------------------
// Wave-per-row softmax: scores [8192 rows][2048] f16 -> P f16. 8 rows/block.
__global__ __launch_bounds__(512) void softmax_rows(
    const _Float16* __restrict__ S, _Float16* __restrict__ P)
{
  const int w = threadIdx.x >> 6, lane = threadIdx.x & 63;
  const size_t row = (size_t)blockIdx.x * 8 + w;
  const _Float16* sr = S + row * 2048;

  f16x8 v[4];
  #pragma unroll
  for (int c = 0; c < 4; ++c)
    v[c] = *(const f16x8*)(sr + c * 512 + lane * 8);

  float m = -1e30f;
  #pragma unroll
  for (int c = 0; c < 4; ++c)
    #pragma unroll
    for (int j = 0; j < 8; ++j) m = fmaxf(m, (float)v[c][j]);
  #pragma unroll
  for (int o = 32; o >= 1; o >>= 1) m = fmaxf(m, __shfl_xor(m, o));

  float e[4][8];
  float s = 0.f;
  #pragma unroll
  for (int c = 0; c < 4; ++c)
    #pragma unroll
    for (int j = 0; j < 8; ++j) {
      e[c][j] = __expf((float)v[c][j] - m);
      s += e[c][j];
    }
  #pragma unroll
  for (int o = 32; o >= 1; o >>= 1) s += __shfl_xor(s, o);

  const float inv = 1.0f / s;
  _Float16* pr = P + row * 2048;
  #pragma unroll
  for (int c = 0; c < 4; ++c) {
    f16x8 p;
    #pragma unroll
    for (int j = 0; j < 8; ++j) p[j] = (_Float16)(e[c][j] * inv);
    *(f16x8*)(pr + c * 512 + lane * 8) = p;
  }
}

// ---------------------------------------------------------------------------
extern "C" void kernel_launch(void* const* d_in, const int* in_sizes, int n_in,
                              void* d_out, int out_size, void* d_ws, size_t ws_size,
                              hipStream_t stream)
{
  const float* Xk = (const float*)d_in[0];
  const float* Xv = (const float*)d_in[1];
  const float* Xq = (const float*)d_in[2];
  const float* WK = (const float*)d_in[3];
  const float* WV = (const float*)d_in[4];
  const float* WQ = (const float*)d_in[5];
  float* out = (float*)d_out;
  char* ws = (char*)d_ws;

  _Float16* XF   = (_Float16*)(ws);               // 0..48 MiB (k,v,q)
  _Float16* WT   = (_Float16*)(ws + 48 * MiB);    // 48..54 (K,V,Q)
  _Float16* PROJ = (_Float16*)(ws + 54 * MiB);    // 54..86 (K,Q)
  _Float16* VTb  = (_Float16*)(ws + 86 * MiB);    // 86..102 [4][1024][2048]
  _Float16* SC   = (_Float16*)(ws + 102 * MiB);   // 102..134 (f16 scores)
  _Float16* P    = (_Float16*)(ws);               // alias XF (dead post-proj)

  _Float16* Kp = PROJ;            // [8192][1024]
  _Float16* Qp = PROJ + MK;       // [8192][1024]

  auto* g1 = gemm8p<1>;
  auto* g2 = gemm8p<2>;
  auto* f1 = gemmO<1>;
  auto* f0 = gemmO<0>;
  (void)hipFuncSetAttribute((const void*)g1, hipFuncAttributeMaxDynamicSharedMemorySize, 131072);
  (void)hipFuncSetAttribute((const void*)g2, hipFuncAttributeMaxDynamicSharedMemorySize, 131072);
  (void)hipFuncSetAttribute((const void*)f1, hipFuncAttributeMaxDynamicSharedMemorySize, 73728);
  (void)hipFuncSetAttribute((const void*)f0, hipFuncAttributeMaxDynamicSharedMemorySize, 73728);

  // 1) prep: W^T tiles first (tail-hidden), then X -> f16 (NT loads only)
  prep<<<dim3(6912), 256, 0, stream>>>(Xk, Xv, Xq, XF, WK, WV, WQ, WT);
  // 2) K,Q projections on gemm8p: (4,32,2) = 256 blocks = 1.0 round
  gemm8p<1><<<dim3(4, 32, 2), 512, 131072, stream>>>(
      XF, 2 * MK, WT, 2 * WSZ, PROJ, MK, 1024, 1024, 1.0f);
  // 3) V^T projection, per-batch contiguous: VTb[b][e][s] = sum_k
  //    WT_V[e][k] * XF_v[b*2048+s][k].  grid (16,4,4) = 256 blocks.
  gemmO<1><<<dim3(16, 4, 4), 512, 73728, stream>>>(
      WT + WSZ, 0, 1024, XF + MK, (size_t)2048 * 1024, 1024,
      VTb, (size_t)1024 * 2048, 2048, 1024, 1.0f);
  // 4) scores[b] = Q[b]@K[b]^T / sqrt(2048) -> f16  (256 blocks)
  gemm8p<2><<<dim3(8, 8, 4), 512, 131072, stream>>>(
      Qp, (size_t)2048 * 1024, Kp, (size_t)2048 * 1024,
      SC, (size_t)2048 * 2048, 2048, 1024, 0.022097086912079608f);
  // 5) softmax (wave-per-row, 8 rows/block) -> P f16
  softmax_rows<<<dim3(1024), 512, 0, stream>>>(SC, P);
  // 6) out[b] = P[b] @ V[b]: B = VTb[b] contiguous ldb=2048
  gemmO<0><<<dim3(8, 8, 4), 512, 73728, stream>>>(
      P, (size_t)2048 * 2048, 2048, VTb, (size_t)1024 * 2048, 2048,
      out, (size_t)2048 * 1024, 1024, 2048, 1.0f);
}